// Round 12
// baseline (360.157 us; speedup 1.0000x reference)
//
#include <hip/hip_runtime.h>
#include <hip/hip_bf16.h>

#define N_NODES 100000
#define D_IN 128
#define D_HID 256
#define D_OUTC 128
#define BN_EPS 1e-5f
#define NBUK 782      // ceil(100000 / 128) buckets of 128 rows
#define BCHUNK 4096   // edges per bin block
#define NGB 782       // gemm row-blocks (128 rows each)
#define NRED 64       // stage-A reduction blocks
#define ROWS_PER 13   // ceil(NGB / NRED)
#define NVB 6250      // conv_v blocks (N*16/256)

typedef __attribute__((ext_vector_type(8))) short short8;
typedef __attribute__((ext_vector_type(4))) float f32x4;

__device__ __forceinline__ unsigned short f2bf(float f) {
  unsigned int u = __float_as_uint(f);
  unsigned int r = u + 0x7fffu + ((u >> 16) & 1u);
  return (unsigned short)(r >> 16);
}
__device__ __forceinline__ float bf2f(unsigned int h) {
  return __uint_as_float(h << 16);
}

// ============ fused conv: v -> v_bf ; W1/W2 -> w1t/w2t (transposed bf16) ============
__global__ __launch_bounds__(256) void conv_kernel(const float* __restrict__ v,
                                                   unsigned short* __restrict__ v_bf,
                                                   const float* __restrict__ W1,
                                                   const float* __restrict__ W2,
                                                   unsigned short* __restrict__ w1t,
                                                   unsigned short* __restrict__ w2t) {
  int b = blockIdx.x;
  if (b < NVB) {
    int i = b * 256 + threadIdx.x;
    const float4* v4 = reinterpret_cast<const float4*>(v);
    float4 a = v4[i * 2];
    float4 c = v4[i * 2 + 1];
    short8 o;
    o[0] = (short)f2bf(a.x); o[1] = (short)f2bf(a.y);
    o[2] = (short)f2bf(a.z); o[3] = (short)f2bf(a.w);
    o[4] = (short)f2bf(c.x); o[5] = (short)f2bf(c.y);
    o[6] = (short)f2bf(c.z); o[7] = (short)f2bf(c.w);
    *reinterpret_cast<short8*>(v_bf + (size_t)i * 8) = o;
  } else {
    int idx = (b - NVB) * 256 + threadIdx.x;
    if (idx < 128 * 256) {
      int n = idx >> 7, k = idx & 127;
      w1t[idx] = f2bf(W1[(size_t)k * 256 + n]);
    } else {
      int i2 = idx - 128 * 256;
      int n = i2 >> 8, k = i2 & 255;
      w2t[i2] = f2bf(W2[(size_t)k * 128 + n]);
    }
  }
}

// ============ bucket histogram ============
__global__ __launch_bounds__(256) void hist_kernel(const int* __restrict__ erows,
                                                   int* __restrict__ bucket_cnt, int E) {
  __shared__ int lh[NBUK];
  int tid = threadIdx.x;
  for (int b = tid; b < NBUK; b += 256) lh[b] = 0;
  __syncthreads();
  for (int e = blockIdx.x * 256 + tid; e < E; e += gridDim.x * 256)
    atomicAdd(&lh[erows[e] >> 7], 1);
  __syncthreads();
  for (int b = tid; b < NBUK; b += 256) {
    int h = lh[b];
    if (h) atomicAdd(&bucket_cnt[b], h);
  }
}

// ============ bucket scan ============
__global__ __launch_bounds__(256) void scan_kernel(const int* __restrict__ bucket_cnt,
                                                   int* __restrict__ bucket_start,
                                                   int* __restrict__ gcursor) {
  __shared__ int psum[256];
  int tid = threadIdx.x;
  int c4[4];
  int s = 0;
#pragma unroll
  for (int m = 0; m < 4; ++m) {
    int b = tid * 4 + m;
    c4[m] = (b < NBUK) ? bucket_cnt[b] : 0;
    s += c4[m];
  }
  psum[tid] = s;
  __syncthreads();
  for (int off = 1; off < 256; off <<= 1) {
    int t2 = (tid >= off) ? psum[tid - off] : 0;
    __syncthreads();
    psum[tid] += t2;
    __syncthreads();
  }
  int run = psum[tid] - s;
#pragma unroll
  for (int m = 0; m < 4; ++m) {
    int b = tid * 4 + m;
    if (b < NBUK) {
      bucket_start[b] = run;
      gcursor[b] = run;
      run += c4[m];
    }
  }
  if (tid == 255) bucket_start[NBUK] = run;  // = E
}

// ============ bin: LDS-staged bucket append with coalesced runs ============
__global__ __launch_bounds__(256) void bin_kernel(const int* __restrict__ erows,
                                                  const int* __restrict__ ecols,
                                                  const float* __restrict__ evals,
                                                  int* __restrict__ gcursor,
                                                  uint2* __restrict__ spack, int E) {
  __shared__ int lhist[NBUK], lpref[NBUK], lcur[NBUK], gbase[NBUK];
  __shared__ int psum[256];
  __shared__ uint2 pay[BCHUNK];
  __shared__ int dst[BCHUNK];
  int tid = threadIdx.x;
  int base = blockIdx.x * BCHUNK;
  int cnt = min(BCHUNK, E - base);

  for (int b = tid; b < NBUK; b += 256) lhist[b] = 0;
  __syncthreads();
#pragma unroll
  for (int k = 0; k < BCHUNK / 256; ++k) {
    int e = base + k * 256 + tid;
    if (e < E) atomicAdd(&lhist[erows[e] >> 7], 1);
  }
  __syncthreads();
  int c4[4];
  int s = 0;
#pragma unroll
  for (int m = 0; m < 4; ++m) {
    int b = tid * 4 + m;
    c4[m] = (b < NBUK) ? lhist[b] : 0;
    s += c4[m];
  }
  psum[tid] = s;
  __syncthreads();
  for (int off = 1; off < 256; off <<= 1) {
    int t2 = (tid >= off) ? psum[tid - off] : 0;
    __syncthreads();
    psum[tid] += t2;
    __syncthreads();
  }
  int run = psum[tid] - s;
#pragma unroll
  for (int m = 0; m < 4; ++m) {
    int b = tid * 4 + m;
    if (b < NBUK) {
      lpref[b] = run;
      lcur[b] = run;
      run += c4[m];
    }
  }
  for (int b = tid; b < NBUK; b += 256) {
    int h = lhist[b];
    gbase[b] = h ? atomicAdd(&gcursor[b], h) : 0;
  }
  __syncthreads();
#pragma unroll
  for (int k = 0; k < BCHUNK / 256; ++k) {
    int e = base + k * 256 + tid;
    if (e < E) {
      int row = erows[e];
      int b = row >> 7, rl = row & 127;
      int pos = atomicAdd(&lcur[b], 1);
      pay[pos] = make_uint2((unsigned)ecols[e] | ((unsigned)rl << 17),
                            __float_as_uint(evals[e]));
      dst[pos] = gbase[b] + (pos - lpref[b]);
    }
  }
  __syncthreads();
  for (int i = tid; i < cnt; i += 256) spack[dst[i]] = pay[i];
}

// ============ sort: within-bucket counting sort to node order + node row_start ============
__global__ __launch_bounds__(256) void sort_kernel(const int* __restrict__ bucket_start,
                                                   const uint2* __restrict__ spack,
                                                   uint2* __restrict__ spack2,
                                                   int* __restrict__ row_start) {
  __shared__ int lhist[128], lcur[128], buf[128];
  int tid = threadIdx.x;
  int bid = blockIdx.x;
  int s = bucket_start[bid], e = bucket_start[bid + 1];
  if (tid < 128) lhist[tid] = 0;
  __syncthreads();
  for (int i = s + tid; i < e; i += 256)
    atomicAdd(&lhist[(spack[i].x >> 17) & 127], 1);
  __syncthreads();
  if (tid < 128) buf[tid] = lhist[tid];
  __syncthreads();
  for (int off = 1; off < 128; off <<= 1) {
    int t = (tid >= off && tid < 128) ? buf[tid - off] : 0;
    __syncthreads();
    if (tid < 128) buf[tid] += t;
    __syncthreads();
  }
  if (tid < 128) {
    int excl = buf[tid] - lhist[tid];
    lcur[tid] = excl;
    int grow = bid * 128 + tid;
    if (grow <= N_NODES) row_start[grow] = s + excl;
  }
  __syncthreads();
  for (int i = s + tid; i < e; i += 256) {
    uint2 p = spack[i];
    int rl = (p.x >> 17) & 127;
    int pos = atomicAdd(&lcur[rl], 1);
    spack2[s + pos] = make_uint2(p.x & 0x1FFFFu, p.y);
  }
}

// ============ FUSED gather + GEMM1 ============
// Per block: 128 rows. Phase 1: each wave gathers its 32 nodes into a swizzled
// 32KB LDS agg tile (identical math to standalone gather, incl. bf16 rounding).
// Phase 2: A-frags LDS->regs, then two sequential 32KB W1-half stages:
// MFMA -> repack -> coalesced h1 store -> LDS column stats.
__global__ __launch_bounds__(256) void gather_gemm1_kernel(
    const int* __restrict__ row_start, const uint2* __restrict__ spack2,
    const unsigned short* __restrict__ v_bf, const float* __restrict__ eps_p,
    const unsigned short* __restrict__ w1t, const float* __restrict__ b1,
    unsigned short* __restrict__ h1_bf, float* __restrict__ pstats1) {
  __shared__ unsigned char smem[32768];
  int tid = threadIdx.x;
  int wid = tid >> 6;
  int lane = tid & 63;
  int m15 = lane & 15;
  int g16 = (lane >> 4) * 16;
  int q4 = lane >> 4;
  int half = lane >> 5;
  int l5 = lane & 31;
  int bx = blockIdx.x;
  int row0 = bx * 128;
  int wrow = row0 + wid * 32;
  const uint2* v64 = reinterpret_cast<const uint2*>(v_bf);
  float eps = eps_p[0];

  // ---- Phase 1: gather 32 nodes per wave into LDS agg (swizzled rows) ----
  for (int i = 0; i < 32; ++i) {
    int n = wrow + i;
    int rl = wid * 32 + i;
    float a0 = 0.f, a1 = 0.f, a2 = 0.f, a3 = 0.f;
    if (n < N_NODES) {
      int s = row_start[n];
      int end = row_start[n + 1];
      for (int e = s; e < end; e += 8) {
        uint2 p[4];
#pragma unroll
        for (int j = 0; j < 4; ++j) p[j] = spack2[min(e + 2 * j + half, end - 1)];
        uint2 t[4];
#pragma unroll
        for (int j = 0; j < 4; ++j) t[j] = v64[(size_t)p[j].x * 32 + l5];
#pragma unroll
        for (int j = 0; j < 4; ++j) {
          float w = (e + 2 * j + half < end) ? __uint_as_float(p[j].y) : 0.f;
          a0 += w * bf2f(t[j].x & 0xffffu);
          a1 += w * bf2f(t[j].x >> 16);
          a2 += w * bf2f(t[j].y & 0xffffu);
          a3 += w * bf2f(t[j].y >> 16);
        }
      }
      a0 += __shfl_xor(a0, 32);
      a1 += __shfl_xor(a1, 32);
      a2 += __shfl_xor(a2, 32);
      a3 += __shfl_xor(a3, 32);
      if (half == 0) {
        uint2 tv = v64[(size_t)n * 32 + l5];
        a0 += eps * bf2f(tv.x & 0xffffu);
        a1 += eps * bf2f(tv.x >> 16);
        a2 += eps * bf2f(tv.y & 0xffffu);
        a3 += eps * bf2f(tv.y >> 16);
      }
    }
    if (half == 0) {
      uint2 o;
      o.x = (unsigned)f2bf(a0) | ((unsigned)f2bf(a1) << 16);
      o.y = (unsigned)f2bf(a2) | ((unsigned)f2bf(a3) << 16);
      *reinterpret_cast<uint2*>(smem + rl * 256 + ((l5 * 8) ^ ((rl & 7) << 4))) = o;
    }
  }
  __syncthreads();

  // ---- A-frags from LDS agg to registers ----
  short8 af0[4], af1[4];
  {
    int r0l = wid * 32 + m15;
    int r1l = r0l + 16;
#pragma unroll
    for (int s = 0; s < 4; ++s) {
      af0[s] = *reinterpret_cast<const short8*>(
          smem + r0l * 256 + ((g16 + s * 64) ^ ((r0l & 7) << 4)));
      af1[s] = *reinterpret_cast<const short8*>(
          smem + r1l * 256 + ((g16 + s * 64) ^ ((r1l & 7) << 4)));
    }
  }
  __syncthreads();  // agg consumed; smem free

  // ---- Phase 2: two W1 column-halves, sequential ----
  for (int ch = 0; ch < 2; ++ch) {
    {
      const float4* src = reinterpret_cast<const float4*>(w1t + (size_t)ch * 128 * 128);
#pragma unroll
      for (int it = 0; it < 8; ++it) {
        int i = it * 256 + tid;
        int lrow = i >> 4;
        int cb = (i & 15) << 4;
        *reinterpret_cast<float4*>(smem + lrow * 256 + (cb ^ ((lrow & 7) << 4))) = src[i];
      }
    }
    __syncthreads();

    f32x4 acc0[8], acc1[8];
#pragma unroll
    for (int t = 0; t < 8; ++t) {
      acc0[t] = (f32x4){0.f, 0.f, 0.f, 0.f};
      acc1[t] = (f32x4){0.f, 0.f, 0.f, 0.f};
    }
#pragma unroll
    for (int s = 0; s < 4; ++s) {
#pragma unroll
      for (int t = 0; t < 8; ++t) {
        int lrow = t * 16 + m15;
        short8 b = *reinterpret_cast<const short8*>(
            smem + lrow * 256 + ((s * 64 + g16) ^ ((lrow & 7) << 4)));
        acc0[t] = __builtin_amdgcn_mfma_f32_16x16x32_bf16(af0[s], b, acc0[t], 0, 0, 0);
        acc1[t] = __builtin_amdgcn_mfma_f32_16x16x32_bf16(af1[s], b, acc1[t], 0, 0, 0);
      }
    }
    __syncthreads();  // B dead; reuse smem for 128x128 bf16 repack

    unsigned short* lds16 = reinterpret_cast<unsigned short*>(smem);
#pragma unroll
    for (int t = 0; t < 8; ++t) {
      int lcol = t * 16 + m15;
      float bias = b1[ch * 128 + lcol];
      int sw = lcol ^ (q4 << 4);
#pragma unroll
      for (int r = 0; r < 4; ++r) {
        int rl0 = wid * 32 + q4 * 4 + r;
        int rl1 = rl0 + 16;
        lds16[rl0 * 128 + sw] = f2bf(acc0[t][r] + bias);
        lds16[rl1 * 128 + sw] = f2bf(acc1[t][r] + bias);
      }
    }
    __syncthreads();
    // coalesced store of the 128x128 col-slice
#pragma unroll
    for (int it = 0; it < 8; ++it) {
      int cid = it * 256 + tid;
      int rl = cid >> 4, c8 = (cid & 15) * 8;
      int row = row0 + rl;
      if (row < N_NODES) {
        *reinterpret_cast<short8*>(h1_bf + (size_t)row * 256 + ch * 128 + c8) =
            *reinterpret_cast<const short8*>(&lds16[rl * 128 + (c8 ^ (((rl >> 2) & 3) << 4))]);
      }
    }
    // partial BN1 stats (R9-style LDS column loop)
    {
      int nvalid = min(128, N_NODES - row0);
      int col = tid & 127, kind = tid >> 7;
      float accv = 0.f;
      for (int rl = 0; rl < nvalid; ++rl) {
        float x = bf2f((unsigned int)lds16[rl * 128 + (col ^ (((rl >> 2) & 3) << 4))]);
        accv += kind ? x * x : x;
      }
      pstats1[(size_t)bx * 512 + ch * 256 + kind * 128 + col] = accv;
    }
    __syncthreads();  // stats done reading before next ch overwrites smem
  }
}

// ============ stage-A reduce: pstats[NGB][W] -> pred[NRED][W] ============
template <int W>
__global__ void reduce_kernel(const float* __restrict__ pstats, float* __restrict__ pred) {
  int j = threadIdx.x;
  int r0 = blockIdx.x * ROWS_PER;
  int r1 = min(r0 + ROWS_PER, NGB);
  float s = 0.f;
  for (int i = r0; i < r1; ++i) s += pstats[(size_t)i * W + j];
  pred[(size_t)blockIdx.x * W + j] = s;
}

// ============ finalize1: reduce NRED partials -> ss1 (scale/shift, 256 cols) ============
__global__ __launch_bounds__(512) void finalize1_kernel(const float* __restrict__ pred,
                                                        const float* __restrict__ g,
                                                        const float* __restrict__ be,
                                                        float* __restrict__ ss) {
  __shared__ float red[512];
  int j = threadIdx.x;
  float s = 0.f;
#pragma unroll 8
  for (int i = 0; i < NRED; ++i) s += pred[(size_t)i * 512 + j];
  red[j] = s;
  __syncthreads();
  if (j < 256) {
    int ch = j >> 7, lc = j & 127;
    float sum = red[ch * 256 + lc];
    float sq = red[ch * 256 + 128 + lc];
    float inv_n = 1.0f / (float)N_NODES;
    float mu = sum * inv_n;
    float var = sq * inv_n - mu * mu;
    float sc = g[j] * rsqrtf(var + BN_EPS);
    ss[j] = sc;
    ss[256 + j] = be[j] - mu * sc;
  }
}

// ============ GEMM2: block = 128 rows x 64 cols (ch half), 32KB LDS (R9 version) ============
__global__ __launch_bounds__(256) void gemm2_kernel(const unsigned short* __restrict__ h1_bf,
                                                    const float* __restrict__ ss1,
                                                    const unsigned short* __restrict__ w2t,
                                                    const float* __restrict__ b2,
                                                    float* __restrict__ out,
                                                    float* __restrict__ pstats2) {
  __shared__ unsigned char smem[32768];
  int tid = threadIdx.x;
  int wid = tid >> 6;
  int lane = tid & 63;
  int m15 = lane & 15;
  int g8 = (lane >> 4) * 8;
  int g16 = (lane >> 4) * 16;
  int q4 = lane >> 4;
  int bx = blockIdx.x, ch = blockIdx.y;
  int row0 = bx * 128;
  int wrow = row0 + wid * 32;

  // upfront raw A loads (2 row-tiles x 8 k-steps)
  short8 a0[8], a1[8];
  {
    const unsigned short* A0 = h1_bf + (size_t)min(wrow + m15, N_NODES - 1) * 256 + g8;
    const unsigned short* A1 = h1_bf + (size_t)min(wrow + 16 + m15, N_NODES - 1) * 256 + g8;
#pragma unroll
    for (int s = 0; s < 8; ++s) {
      a0[s] = *reinterpret_cast<const short8*>(A0 + s * 32);
      a1[s] = *reinterpret_cast<const short8*>(A1 + s * 32);
    }
  }
  // stage w2t rows [ch*64, ch*64+64) (64 x 512B = 32KB), swizzled
  {
    const float4* src = reinterpret_cast<const float4*>(w2t + (size_t)ch * 64 * 256);
#pragma unroll
    for (int it = 0; it < 8; ++it) {
      int i = it * 256 + tid;
      int lrow = i >> 5;
      int cb = (i & 31) << 4;
      *reinterpret_cast<float4*>(smem + lrow * 512 + (cb ^ ((lrow & 7) << 4))) = src[i];
    }
  }
  // BN1+ReLU transform on registers (overlaps staging latency, pre-barrier)
#pragma unroll
  for (int s = 0; s < 8; ++s) {
    int k0 = s * 32 + g8;
    float scv[8], shv[8];
    *reinterpret_cast<float4*>(&scv[0]) = *reinterpret_cast<const float4*>(ss1 + k0);
    *reinterpret_cast<float4*>(&scv[4]) = *reinterpret_cast<const float4*>(ss1 + k0 + 4);
    *reinterpret_cast<float4*>(&shv[0]) = *reinterpret_cast<const float4*>(ss1 + 256 + k0);
    *reinterpret_cast<float4*>(&shv[4]) = *reinterpret_cast<const float4*>(ss1 + 256 + k0 + 4);
#pragma unroll
    for (int j = 0; j < 8; ++j) {
      a0[s][j] = (short)f2bf(fmaxf(bf2f((unsigned int)(unsigned short)a0[s][j]) * scv[j] + shv[j], 0.f));
      a1[s][j] = (short)f2bf(fmaxf(bf2f((unsigned int)(unsigned short)a1[s][j]) * scv[j] + shv[j], 0.f));
    }
  }
  __syncthreads();

  f32x4 acc0[4], acc1[4];
#pragma unroll
  for (int t = 0; t < 4; ++t) {
    acc0[t] = (f32x4){0.f, 0.f, 0.f, 0.f};
    acc1[t] = (f32x4){0.f, 0.f, 0.f, 0.f};
  }
#pragma unroll
  for (int s = 0; s < 8; ++s) {
#pragma unroll
    for (int t = 0; t < 4; ++t) {
      int lrow = t * 16 + m15;
      short8 b = *reinterpret_cast<const short8*>(
          smem + lrow * 512 + ((s * 64 + g16) ^ ((lrow & 7) << 4)));
      acc0[t] = __builtin_amdgcn_mfma_f32_16x16x32_bf16(a0[s], b, acc0[t], 0, 0, 0);
      acc1[t] = __builtin_amdgcn_mfma_f32_16x16x32_bf16(a1[s], b, acc1[t], 0, 0, 0);
    }
  }
  __syncthreads();  // B dead; reuse for 128x64 fp32 repack (32KB)

  float* ldsf = reinterpret_cast<float*>(smem);
#pragma unroll
  for (int t = 0; t < 4; ++t) {
    int lcol = t * 16 + m15;
    float bias = b2[ch * 64 + lcol];
    int sw = lcol ^ (q4 << 4);
#pragma unroll
    for (int r = 0; r < 4; ++r) {
      int rl0 = wid * 32 + q4 * 4 + r;
      int rl1 = rl0 + 16;
      ldsf[rl0 * 64 + sw] = acc0[t][r] + bias;
      ldsf[rl1 * 64 + sw] = acc1[t][r] + bias;
    }
  }
  __syncthreads();
  // coalesced store of the 128x64 col-slice
#pragma unroll
  for (int it = 0; it < 8; ++it) {
    int cid = it * 256 + tid;
    int rl = cid >> 4, c4 = (cid & 15) * 4;
    int row = row0 + rl;
    if (row < N_NODES) {
      *reinterpret_cast<float4*>(out + (size_t)row * 128 + ch * 64 + c4) =
          *reinterpret_cast<const float4*>(&ldsf[rl * 64 + (c4 ^ (((rl >> 2) & 3) << 4))]);
    }
  }
  // partial BN2 stats: threads 0..63 sums, 64..127 sumsq
  if (tid < 128) {
    int nvalid = min(128, N_NODES - row0);
    int col = tid & 63, kind = tid >> 6;
    float acc = 0.f;
    for (int rl = 0; rl < nvalid; ++rl) {
      float x = ldsf[rl * 64 + (col ^ (((rl >> 2) & 3) << 4))];
      acc += kind ? x * x : x;
    }
    pstats2[(size_t)bx * 256 + ch * 128 + kind * 64 + col] = acc;
  }
}

// ============ finalize2: reduce NRED partials -> ss2 (128 cols) ============
__global__ __launch_bounds__(256) void finalize2_kernel(const float* __restrict__ pred,
                                                        const float* __restrict__ g,
                                                        const float* __restrict__ be,
                                                        float* __restrict__ ss) {
  __shared__ float red[256];
  int j = threadIdx.x;
  float s = 0.f;
#pragma unroll 8
  for (int i = 0; i < NRED; ++i) s += pred[(size_t)i * 256 + j];
  red[j] = s;
  __syncthreads();
  if (j < 128) {
    int ch = j >> 6, lc = j & 63;
    float sum = red[ch * 128 + lc];
    float sq = red[ch * 128 + 64 + lc];
    float inv_n = 1.0f / (float)N_NODES;
    float mu = sum * inv_n;
    float var = sq * inv_n - mu * mu;
    float sc = g[j] * rsqrtf(var + BN_EPS);
    ss[j] = sc;
    ss[128 + j] = be[j] - mu * sc;
  }
}

__global__ __launch_bounds__(256) void bnrelu_kernel(float* __restrict__ out,
                                                     const float* __restrict__ ss) {
  __shared__ float sc[D_OUTC], sh[D_OUTC];
  if (threadIdx.x < D_OUTC) {
    sc[threadIdx.x] = ss[threadIdx.x];
    sh[threadIdx.x] = ss[D_OUTC + threadIdx.x];
  }
  __syncthreads();
  size_t total = (size_t)N_NODES * (D_OUTC / 4);
  for (size_t i = (size_t)blockIdx.x * blockDim.x + threadIdx.x; i < total;
       i += (size_t)gridDim.x * blockDim.x) {
    float4 o = reinterpret_cast<float4*>(out)[i];
    int c = ((int)(i & 31)) * 4;
    o.x = fmaxf(o.x * sc[c + 0] + sh[c + 0], 0.f);
    o.y = fmaxf(o.y * sc[c + 1] + sh[c + 1], 0.f);
    o.z = fmaxf(o.z * sc[c + 2] + sh[c + 2], 0.f);
    o.w = fmaxf(o.w * sc[c + 3] + sh[c + 3], 0.f);
    reinterpret_cast<float4*>(out)[i] = o;
  }
}

extern "C" void kernel_launch(void* const* d_in, const int* in_sizes, int n_in,
                              void* d_out, int out_size, void* d_ws, size_t ws_size,
                              hipStream_t stream) {
  const float* v = (const float*)d_in[0];
  const int* erows = (const int*)d_in[1];
  const int* ecols = (const int*)d_in[2];
  const float* evals = (const float*)d_in[3];
  const float* eps = (const float*)d_in[4];
  const float* W1 = (const float*)d_in[5];
  const float* b1 = (const float*)d_in[6];
  const float* g1 = (const float*)d_in[7];
  const float* be1 = (const float*)d_in[8];
  const float* W2 = (const float*)d_in[9];
  const float* b2 = (const float*)d_in[10];
  const float* g2 = (const float*)d_in[11];
  const float* be2 = (const float*)d_in[12];
  float* out = (float*)d_out;
  int E = in_sizes[1];

  // Layout (fused kernel reads v_bf+spack2, writes h1+pstats1 — no overlap):
  char* ws = (char*)d_ws;
  unsigned short* v_bf = (unsigned short*)(ws + 0);          // 25.6 MB
  uint2* spack2 = (uint2*)(ws + 25600000);                   // 12.8 MB
  unsigned short* h1_bf = (unsigned short*)(ws + 38400000);  // 51.2 MB -> ends 89.6M
  uint2* spack = (uint2*)(ws + 89600000);                    // 12.8 MB (dead after sort)
  float* pstats1 = (float*)(ws + 89600000);                  // overlay spack
  float* pstats2 = (float*)(ws + 91201536);
  float* pred1 = (float*)(ws + 92002304);
  float* pred2 = (float*)(ws + 92133376);
  unsigned short* w1t = (unsigned short*)(ws + 102400000);
  unsigned short* w2t = (unsigned short*)(ws + 102465536);
  float* ss1 = (float*)(ws + 102533120);
  float* ss2 = (float*)(ws + 102536192);
  int* bucket_cnt = (int*)(ws + 102537216);    // 782 ints
  int* bucket_start = (int*)(ws + 102540352);  // 783 ints
  int* gcursor = (int*)(ws + 102543488);       // 782 ints
  int* row_start = (int*)(ws + 102546688);     // 100001 ints

  hipMemsetAsync(bucket_cnt, 0, NBUK * sizeof(int), stream);

  conv_kernel<<<NVB + 256, 256, 0, stream>>>(v, v_bf, W1, W2, w1t, w2t);

  hist_kernel<<<256, 256, 0, stream>>>(erows, bucket_cnt, E);
  scan_kernel<<<1, 256, 0, stream>>>(bucket_cnt, bucket_start, gcursor);
  bin_kernel<<<(E + BCHUNK - 1) / BCHUNK, 256, 0, stream>>>(erows, ecols, evals, gcursor, spack, E);
  sort_kernel<<<NBUK, 256, 0, stream>>>(bucket_start, spack, spack2, row_start);

  gather_gemm1_kernel<<<NGB, 256, 0, stream>>>(row_start, spack2, v_bf, eps, w1t, b1,
                                               h1_bf, pstats1);
  reduce_kernel<512><<<NRED, 512, 0, stream>>>(pstats1, pred1);
  finalize1_kernel<<<1, 512, 0, stream>>>(pred1, g1, be1, ss1);
  gemm2_kernel<<<dim3(NGB, 2), 256, 0, stream>>>(h1_bf, ss1, w2t, b2, out, pstats2);
  reduce_kernel<256><<<NRED, 256, 0, stream>>>(pstats2, pred2);
  finalize2_kernel<<<1, 256, 0, stream>>>(pred2, g2, be2, ss2);
  bnrelu_kernel<<<2048, 256, 0, stream>>>(out, ss2);
}

// Round 13
// 243.821 us; speedup vs baseline: 1.4771x; 1.4771x over previous
//
#include <hip/hip_runtime.h>
#include <hip/hip_bf16.h>

#define N_NODES 100000
#define D_IN 128
#define D_HID 256
#define D_OUTC 128
#define BN_EPS 1e-5f
#define NBUK 782      // ceil(100000 / 128) buckets of 128 rows
#define BCHUNK 4096   // edges per bin block
#define NGB 782       // gemm row-blocks (128 rows each)
#define NRED 64       // stage-A reduction blocks
#define ROWS_PER 13   // ceil(NGB / NRED)
#define NVB 6250      // conv_v blocks (N*16/256)

typedef __attribute__((ext_vector_type(8))) short short8;
typedef __attribute__((ext_vector_type(4))) float f32x4;

__device__ __forceinline__ unsigned short f2bf(float f) {
  unsigned int u = __float_as_uint(f);
  unsigned int r = u + 0x7fffu + ((u >> 16) & 1u);
  return (unsigned short)(r >> 16);
}
__device__ __forceinline__ float bf2f(unsigned int h) {
  return __uint_as_float(h << 16);
}

// ===== fused conv + bucket-hist: blocks [0,NVB) convert v; [NVB,NVB+256) convert W;
// ===== [NVB+256,NVB+512) histogram edge rows into buckets.
__global__ __launch_bounds__(256) void conv_kernel(const float* __restrict__ v,
                                                   unsigned short* __restrict__ v_bf,
                                                   const float* __restrict__ W1,
                                                   const float* __restrict__ W2,
                                                   unsigned short* __restrict__ w1t,
                                                   unsigned short* __restrict__ w2t,
                                                   const int* __restrict__ erows,
                                                   int* __restrict__ bucket_cnt, int E) {
  __shared__ int lh[NBUK];
  int b = blockIdx.x;
  int tid = threadIdx.x;
  if (b < NVB) {
    int i = b * 256 + tid;
    const float4* v4 = reinterpret_cast<const float4*>(v);
    float4 a = v4[i * 2];
    float4 c = v4[i * 2 + 1];
    short8 o;
    o[0] = (short)f2bf(a.x); o[1] = (short)f2bf(a.y);
    o[2] = (short)f2bf(a.z); o[3] = (short)f2bf(a.w);
    o[4] = (short)f2bf(c.x); o[5] = (short)f2bf(c.y);
    o[6] = (short)f2bf(c.z); o[7] = (short)f2bf(c.w);
    *reinterpret_cast<short8*>(v_bf + (size_t)i * 8) = o;
  } else if (b < NVB + 256) {
    int idx = (b - NVB) * 256 + tid;
    if (idx < 128 * 256) {
      int n = idx >> 7, k = idx & 127;
      w1t[idx] = f2bf(W1[(size_t)k * 256 + n]);
    } else {
      int i2 = idx - 128 * 256;
      int n = i2 >> 8, k = i2 & 255;
      w2t[i2] = f2bf(W2[(size_t)k * 128 + n]);
    }
  } else {
    int hb = b - NVB - 256;  // 0..255
    for (int j = tid; j < NBUK; j += 256) lh[j] = 0;
    __syncthreads();
    for (int e = hb * 256 + tid; e < E; e += 256 * 256)
      atomicAdd(&lh[erows[e] >> 7], 1);
    __syncthreads();
    for (int j = tid; j < NBUK; j += 256) {
      int h = lh[j];
      if (h) atomicAdd(&bucket_cnt[j], h);
    }
  }
}

// ============ bucket scan ============
__global__ __launch_bounds__(256) void scan_kernel(const int* __restrict__ bucket_cnt,
                                                   int* __restrict__ bucket_start,
                                                   int* __restrict__ gcursor) {
  __shared__ int psum[256];
  int tid = threadIdx.x;
  int c4[4];
  int s = 0;
#pragma unroll
  for (int m = 0; m < 4; ++m) {
    int b = tid * 4 + m;
    c4[m] = (b < NBUK) ? bucket_cnt[b] : 0;
    s += c4[m];
  }
  psum[tid] = s;
  __syncthreads();
  for (int off = 1; off < 256; off <<= 1) {
    int t2 = (tid >= off) ? psum[tid - off] : 0;
    __syncthreads();
    psum[tid] += t2;
    __syncthreads();
  }
  int run = psum[tid] - s;
#pragma unroll
  for (int m = 0; m < 4; ++m) {
    int b = tid * 4 + m;
    if (b < NBUK) {
      bucket_start[b] = run;
      gcursor[b] = run;
      run += c4[m];
    }
  }
  if (tid == 255) bucket_start[NBUK] = run;  // = E
}

// ============ bin: LDS-staged bucket append with coalesced runs ============
__global__ __launch_bounds__(256) void bin_kernel(const int* __restrict__ erows,
                                                  const int* __restrict__ ecols,
                                                  const float* __restrict__ evals,
                                                  int* __restrict__ gcursor,
                                                  uint2* __restrict__ spack, int E) {
  __shared__ int lhist[NBUK], lpref[NBUK], lcur[NBUK], gbase[NBUK];
  __shared__ int psum[256];
  __shared__ uint2 pay[BCHUNK];
  __shared__ int dst[BCHUNK];
  int tid = threadIdx.x;
  int base = blockIdx.x * BCHUNK;
  int cnt = min(BCHUNK, E - base);

  for (int b = tid; b < NBUK; b += 256) lhist[b] = 0;
  __syncthreads();
#pragma unroll
  for (int k = 0; k < BCHUNK / 256; ++k) {
    int e = base + k * 256 + tid;
    if (e < E) atomicAdd(&lhist[erows[e] >> 7], 1);
  }
  __syncthreads();
  int c4[4];
  int s = 0;
#pragma unroll
  for (int m = 0; m < 4; ++m) {
    int b = tid * 4 + m;
    c4[m] = (b < NBUK) ? lhist[b] : 0;
    s += c4[m];
  }
  psum[tid] = s;
  __syncthreads();
  for (int off = 1; off < 256; off <<= 1) {
    int t2 = (tid >= off) ? psum[tid - off] : 0;
    __syncthreads();
    psum[tid] += t2;
    __syncthreads();
  }
  int run = psum[tid] - s;
#pragma unroll
  for (int m = 0; m < 4; ++m) {
    int b = tid * 4 + m;
    if (b < NBUK) {
      lpref[b] = run;
      lcur[b] = run;
      run += c4[m];
    }
  }
  for (int b = tid; b < NBUK; b += 256) {
    int h = lhist[b];
    gbase[b] = h ? atomicAdd(&gcursor[b], h) : 0;
  }
  __syncthreads();
#pragma unroll
  for (int k = 0; k < BCHUNK / 256; ++k) {
    int e = base + k * 256 + tid;
    if (e < E) {
      int row = erows[e];
      int b = row >> 7, rl = row & 127;
      int pos = atomicAdd(&lcur[b], 1);
      pay[pos] = make_uint2((unsigned)ecols[e] | ((unsigned)rl << 17),
                            __float_as_uint(evals[e]));
      dst[pos] = gbase[b] + (pos - lpref[b]);
    }
  }
  __syncthreads();
  for (int i = tid; i < cnt; i += 256) spack[dst[i]] = pay[i];
}

// ============ sort: within-bucket counting sort to node order + node row_start ============
__global__ __launch_bounds__(256) void sort_kernel(const int* __restrict__ bucket_start,
                                                   const uint2* __restrict__ spack,
                                                   uint2* __restrict__ spack2,
                                                   int* __restrict__ row_start) {
  __shared__ int lhist[128], lcur[128], buf[128];
  int tid = threadIdx.x;
  int bid = blockIdx.x;
  int s = bucket_start[bid], e = bucket_start[bid + 1];
  if (tid < 128) lhist[tid] = 0;
  __syncthreads();
  for (int i = s + tid; i < e; i += 256)
    atomicAdd(&lhist[(spack[i].x >> 17) & 127], 1);
  __syncthreads();
  if (tid < 128) buf[tid] = lhist[tid];
  __syncthreads();
  for (int off = 1; off < 128; off <<= 1) {
    int t = (tid >= off && tid < 128) ? buf[tid - off] : 0;
    __syncthreads();
    if (tid < 128) buf[tid] += t;
    __syncthreads();
  }
  if (tid < 128) {
    int excl = buf[tid] - lhist[tid];
    lcur[tid] = excl;
    int grow = bid * 128 + tid;
    if (grow <= N_NODES) row_start[grow] = s + excl;
  }
  __syncthreads();
  for (int i = s + tid; i < e; i += 256) {
    uint2 p = spack[i];
    int rl = (p.x >> 17) & 127;
    int pos = atomicAdd(&lcur[rl], 1);
    spack2[s + pos] = make_uint2(p.x & 0x1FFFFu, p.y);
  }
}

// ============ node gather: 1 wave/node, 8 edges in flight, register accum ============
__global__ __launch_bounds__(256) void gather_kernel(const int* __restrict__ row_start,
                                                     const uint2* __restrict__ spack2,
                                                     const unsigned short* __restrict__ v_bf,
                                                     const float* __restrict__ eps_p,
                                                     unsigned short* __restrict__ agg_bf) {
  int wid = blockIdx.x * 4 + (threadIdx.x >> 6);
  if (wid >= N_NODES) return;
  int lane = threadIdx.x & 63;
  int half = lane >> 5;
  int l5 = lane & 31;
  int s = row_start[wid];
  int end = row_start[wid + 1];
  const uint2* v64 = reinterpret_cast<const uint2*>(v_bf);

  float a0 = 0.f, a1 = 0.f, a2 = 0.f, a3 = 0.f;
  for (int e = s; e < end; e += 8) {
    uint2 p[4];
#pragma unroll
    for (int j = 0; j < 4; ++j) p[j] = spack2[min(e + 2 * j + half, end - 1)];
    uint2 t[4];
#pragma unroll
    for (int j = 0; j < 4; ++j) t[j] = v64[(size_t)p[j].x * 32 + l5];
#pragma unroll
    for (int j = 0; j < 4; ++j) {
      float w = (e + 2 * j + half < end) ? __uint_as_float(p[j].y) : 0.f;
      a0 += w * bf2f(t[j].x & 0xffffu);
      a1 += w * bf2f(t[j].x >> 16);
      a2 += w * bf2f(t[j].y & 0xffffu);
      a3 += w * bf2f(t[j].y >> 16);
    }
  }
  a0 += __shfl_xor(a0, 32);
  a1 += __shfl_xor(a1, 32);
  a2 += __shfl_xor(a2, 32);
  a3 += __shfl_xor(a3, 32);
  if (half == 0) {
    float eps = eps_p[0];
    uint2 tv = v64[(size_t)wid * 32 + l5];
    a0 += eps * bf2f(tv.x & 0xffffu);
    a1 += eps * bf2f(tv.x >> 16);
    a2 += eps * bf2f(tv.y & 0xffffu);
    a3 += eps * bf2f(tv.y >> 16);
    uint2 o;
    o.x = (unsigned)f2bf(a0) | ((unsigned)f2bf(a1) << 16);
    o.y = (unsigned)f2bf(a2) | ((unsigned)f2bf(a3) << 16);
    reinterpret_cast<uint2*>(agg_bf)[(size_t)wid * 32 + l5] = o;
  }
}

// ============ GEMM1: block = 128 rows x 128 cols (ch half), 32KB LDS ============
__global__ __launch_bounds__(256) void gemm1_kernel(const unsigned short* __restrict__ agg_bf,
                                                    const unsigned short* __restrict__ w1t,
                                                    const float* __restrict__ b1,
                                                    unsigned short* __restrict__ h1_bf,
                                                    float* __restrict__ pstats1) {
  __shared__ unsigned char smem[32768];
  int tid = threadIdx.x;
  int wid = tid >> 6;
  int lane = tid & 63;
  int m15 = lane & 15;
  int g8 = (lane >> 4) * 8;
  int g16 = (lane >> 4) * 16;
  int q4 = lane >> 4;
  int bx = blockIdx.x, ch = blockIdx.y;
  int row0 = bx * 128;
  int wrow = row0 + wid * 32;

  short8 a0[4], a1[4];
  {
    const unsigned short* A0 = agg_bf + (size_t)min(wrow + m15, N_NODES - 1) * 128 + g8;
    const unsigned short* A1 = agg_bf + (size_t)min(wrow + 16 + m15, N_NODES - 1) * 128 + g8;
#pragma unroll
    for (int s = 0; s < 4; ++s) {
      a0[s] = *reinterpret_cast<const short8*>(A0 + s * 32);
      a1[s] = *reinterpret_cast<const short8*>(A1 + s * 32);
    }
  }
  {
    const float4* src = reinterpret_cast<const float4*>(w1t + (size_t)ch * 128 * 128);
#pragma unroll
    for (int it = 0; it < 8; ++it) {
      int i = it * 256 + tid;
      int lrow = i >> 4;
      int cb = (i & 15) << 4;
      *reinterpret_cast<float4*>(smem + lrow * 256 + (cb ^ ((lrow & 7) << 4))) = src[i];
    }
  }
  __syncthreads();

  f32x4 acc0[8], acc1[8];
#pragma unroll
  for (int t = 0; t < 8; ++t) {
    acc0[t] = (f32x4){0.f, 0.f, 0.f, 0.f};
    acc1[t] = (f32x4){0.f, 0.f, 0.f, 0.f};
  }
#pragma unroll
  for (int s = 0; s < 4; ++s) {
#pragma unroll
    for (int t = 0; t < 8; ++t) {
      int lrow = t * 16 + m15;
      short8 b = *reinterpret_cast<const short8*>(
          smem + lrow * 256 + ((s * 64 + g16) ^ ((lrow & 7) << 4)));
      acc0[t] = __builtin_amdgcn_mfma_f32_16x16x32_bf16(a0[s], b, acc0[t], 0, 0, 0);
      acc1[t] = __builtin_amdgcn_mfma_f32_16x16x32_bf16(a1[s], b, acc1[t], 0, 0, 0);
    }
  }
  __syncthreads();  // B dead; reuse for 128x128 bf16 repack (32KB)

  unsigned short* lds16 = reinterpret_cast<unsigned short*>(smem);
#pragma unroll
  for (int t = 0; t < 8; ++t) {
    int lcol = t * 16 + m15;
    float bias = b1[ch * 128 + lcol];
    int sw = lcol ^ (q4 << 4);
#pragma unroll
    for (int r = 0; r < 4; ++r) {
      int rl0 = wid * 32 + q4 * 4 + r;
      int rl1 = rl0 + 16;
      lds16[rl0 * 128 + sw] = f2bf(acc0[t][r] + bias);
      lds16[rl1 * 128 + sw] = f2bf(acc1[t][r] + bias);
    }
  }
  __syncthreads();
#pragma unroll
  for (int it = 0; it < 8; ++it) {
    int cid = it * 256 + tid;
    int rl = cid >> 4, c8 = (cid & 15) * 8;
    int row = row0 + rl;
    if (row < N_NODES) {
      *reinterpret_cast<short8*>(h1_bf + (size_t)row * 256 + ch * 128 + c8) =
          *reinterpret_cast<const short8*>(&lds16[rl * 128 + (c8 ^ (((rl >> 2) & 3) << 4))]);
    }
  }
  {
    int nvalid = min(128, N_NODES - row0);
    int col = tid & 127, kind = tid >> 7;
    float acc = 0.f;
    for (int rl = 0; rl < nvalid; ++rl) {
      float x = bf2f((unsigned int)lds16[rl * 128 + (col ^ (((rl >> 2) & 3) << 4))]);
      acc += kind ? x * x : x;
    }
    pstats1[(size_t)bx * 512 + ch * 256 + kind * 128 + col] = acc;
  }
}

// ============ stage-A reduce: pstats[NGB][W] -> pred[NRED][W] ============
template <int W>
__global__ void reduce_kernel(const float* __restrict__ pstats, float* __restrict__ pred) {
  int j = threadIdx.x;
  int r0 = blockIdx.x * ROWS_PER;
  int r1 = min(r0 + ROWS_PER, NGB);
  float s = 0.f;
  for (int i = r0; i < r1; ++i) s += pstats[(size_t)i * W + j];
  pred[(size_t)blockIdx.x * W + j] = s;
}

// ============ finalize1: reduce NRED partials -> ss1 (scale/shift, 256 cols) ============
__global__ __launch_bounds__(512) void finalize1_kernel(const float* __restrict__ pred,
                                                        const float* __restrict__ g,
                                                        const float* __restrict__ be,
                                                        float* __restrict__ ss) {
  __shared__ float red[512];
  int j = threadIdx.x;
  float s = 0.f;
#pragma unroll 8
  for (int i = 0; i < NRED; ++i) s += pred[(size_t)i * 512 + j];
  red[j] = s;
  __syncthreads();
  if (j < 256) {
    int ch = j >> 7, lc = j & 127;
    float sum = red[ch * 256 + lc];
    float sq = red[ch * 256 + 128 + lc];
    float inv_n = 1.0f / (float)N_NODES;
    float mu = sum * inv_n;
    float var = sq * inv_n - mu * mu;
    float sc = g[j] * rsqrtf(var + BN_EPS);
    ss[j] = sc;
    ss[256 + j] = be[j] - mu * sc;
  }
}

// ============ GEMM2: block = 128 rows x 64 cols (ch half), 32KB LDS ============
__global__ __launch_bounds__(256) void gemm2_kernel(const unsigned short* __restrict__ h1_bf,
                                                    const float* __restrict__ ss1,
                                                    const unsigned short* __restrict__ w2t,
                                                    const float* __restrict__ b2,
                                                    float* __restrict__ out,
                                                    float* __restrict__ pstats2) {
  __shared__ unsigned char smem[32768];
  int tid = threadIdx.x;
  int wid = tid >> 6;
  int lane = tid & 63;
  int m15 = lane & 15;
  int g8 = (lane >> 4) * 8;
  int g16 = (lane >> 4) * 16;
  int q4 = lane >> 4;
  int bx = blockIdx.x, ch = blockIdx.y;
  int row0 = bx * 128;
  int wrow = row0 + wid * 32;

  short8 a0[8], a1[8];
  {
    const unsigned short* A0 = h1_bf + (size_t)min(wrow + m15, N_NODES - 1) * 256 + g8;
    const unsigned short* A1 = h1_bf + (size_t)min(wrow + 16 + m15, N_NODES - 1) * 256 + g8;
#pragma unroll
    for (int s = 0; s < 8; ++s) {
      a0[s] = *reinterpret_cast<const short8*>(A0 + s * 32);
      a1[s] = *reinterpret_cast<const short8*>(A1 + s * 32);
    }
  }
  {
    const float4* src = reinterpret_cast<const float4*>(w2t + (size_t)ch * 64 * 256);
#pragma unroll
    for (int it = 0; it < 8; ++it) {
      int i = it * 256 + tid;
      int lrow = i >> 5;
      int cb = (i & 31) << 4;
      *reinterpret_cast<float4*>(smem + lrow * 512 + (cb ^ ((lrow & 7) << 4))) = src[i];
    }
  }
#pragma unroll
  for (int s = 0; s < 8; ++s) {
    int k0 = s * 32 + g8;
    float scv[8], shv[8];
    *reinterpret_cast<float4*>(&scv[0]) = *reinterpret_cast<const float4*>(ss1 + k0);
    *reinterpret_cast<float4*>(&scv[4]) = *reinterpret_cast<const float4*>(ss1 + k0 + 4);
    *reinterpret_cast<float4*>(&shv[0]) = *reinterpret_cast<const float4*>(ss1 + 256 + k0);
    *reinterpret_cast<float4*>(&shv[4]) = *reinterpret_cast<const float4*>(ss1 + 256 + k0 + 4);
#pragma unroll
    for (int j = 0; j < 8; ++j) {
      a0[s][j] = (short)f2bf(fmaxf(bf2f((unsigned int)(unsigned short)a0[s][j]) * scv[j] + shv[j], 0.f));
      a1[s][j] = (short)f2bf(fmaxf(bf2f((unsigned int)(unsigned short)a1[s][j]) * scv[j] + shv[j], 0.f));
    }
  }
  __syncthreads();

  f32x4 acc0[4], acc1[4];
#pragma unroll
  for (int t = 0; t < 4; ++t) {
    acc0[t] = (f32x4){0.f, 0.f, 0.f, 0.f};
    acc1[t] = (f32x4){0.f, 0.f, 0.f, 0.f};
  }
#pragma unroll
  for (int s = 0; s < 8; ++s) {
#pragma unroll
    for (int t = 0; t < 4; ++t) {
      int lrow = t * 16 + m15;
      short8 b = *reinterpret_cast<const short8*>(
          smem + lrow * 512 + ((s * 64 + g16) ^ ((lrow & 7) << 4)));
      acc0[t] = __builtin_amdgcn_mfma_f32_16x16x32_bf16(a0[s], b, acc0[t], 0, 0, 0);
      acc1[t] = __builtin_amdgcn_mfma_f32_16x16x32_bf16(a1[s], b, acc1[t], 0, 0, 0);
    }
  }
  __syncthreads();  // B dead; reuse for 128x64 fp32 repack (32KB)

  float* ldsf = reinterpret_cast<float*>(smem);
#pragma unroll
  for (int t = 0; t < 4; ++t) {
    int lcol = t * 16 + m15;
    float bias = b2[ch * 64 + lcol];
    int sw = lcol ^ (q4 << 4);
#pragma unroll
    for (int r = 0; r < 4; ++r) {
      int rl0 = wid * 32 + q4 * 4 + r;
      int rl1 = rl0 + 16;
      ldsf[rl0 * 64 + sw] = acc0[t][r] + bias;
      ldsf[rl1 * 64 + sw] = acc1[t][r] + bias;
    }
  }
  __syncthreads();
#pragma unroll
  for (int it = 0; it < 8; ++it) {
    int cid = it * 256 + tid;
    int rl = cid >> 4, c4 = (cid & 15) * 4;
    int row = row0 + rl;
    if (row < N_NODES) {
      *reinterpret_cast<float4*>(out + (size_t)row * 128 + ch * 64 + c4) =
          *reinterpret_cast<const float4*>(&ldsf[rl * 64 + (c4 ^ (((rl >> 2) & 3) << 4))]);
    }
  }
  if (tid < 128) {
    int nvalid = min(128, N_NODES - row0);
    int col = tid & 63, kind = tid >> 6;
    float acc = 0.f;
    for (int rl = 0; rl < nvalid; ++rl) {
      float x = ldsf[rl * 64 + (col ^ (((rl >> 2) & 3) << 4))];
      acc += kind ? x * x : x;
    }
    pstats2[(size_t)bx * 256 + ch * 128 + kind * 64 + col] = acc;
  }
}

// ============ finalize2: reduce NRED partials -> ss2 (128 cols) ============
__global__ __launch_bounds__(256) void finalize2_kernel(const float* __restrict__ pred,
                                                        const float* __restrict__ g,
                                                        const float* __restrict__ be,
                                                        float* __restrict__ ss) {
  __shared__ float red[256];
  int j = threadIdx.x;
  float s = 0.f;
#pragma unroll 8
  for (int i = 0; i < NRED; ++i) s += pred[(size_t)i * 256 + j];
  red[j] = s;
  __syncthreads();
  if (j < 128) {
    int ch = j >> 6, lc = j & 63;
    float sum = red[ch * 128 + lc];
    float sq = red[ch * 128 + 64 + lc];
    float inv_n = 1.0f / (float)N_NODES;
    float mu = sum * inv_n;
    float var = sq * inv_n - mu * mu;
    float sc = g[j] * rsqrtf(var + BN_EPS);
    ss[j] = sc;
    ss[128 + j] = be[j] - mu * sc;
  }
}

__global__ __launch_bounds__(256) void bnrelu_kernel(float* __restrict__ out,
                                                     const float* __restrict__ ss) {
  __shared__ float sc[D_OUTC], sh[D_OUTC];
  if (threadIdx.x < D_OUTC) {
    sc[threadIdx.x] = ss[threadIdx.x];
    sh[threadIdx.x] = ss[D_OUTC + threadIdx.x];
  }
  __syncthreads();
  size_t total = (size_t)N_NODES * (D_OUTC / 4);
  for (size_t i = (size_t)blockIdx.x * blockDim.x + threadIdx.x; i < total;
       i += (size_t)gridDim.x * blockDim.x) {
    float4 o = reinterpret_cast<float4*>(out)[i];
    int c = ((int)(i & 31)) * 4;
    o.x = fmaxf(o.x * sc[c + 0] + sh[c + 0], 0.f);
    o.y = fmaxf(o.y * sc[c + 1] + sh[c + 1], 0.f);
    o.z = fmaxf(o.z * sc[c + 2] + sh[c + 2], 0.f);
    o.w = fmaxf(o.w * sc[c + 3] + sh[c + 3], 0.f);
    reinterpret_cast<float4*>(out)[i] = o;
  }
}

extern "C" void kernel_launch(void* const* d_in, const int* in_sizes, int n_in,
                              void* d_out, int out_size, void* d_ws, size_t ws_size,
                              hipStream_t stream) {
  const float* v = (const float*)d_in[0];
  const int* erows = (const int*)d_in[1];
  const int* ecols = (const int*)d_in[2];
  const float* evals = (const float*)d_in[3];
  const float* eps = (const float*)d_in[4];
  const float* W1 = (const float*)d_in[5];
  const float* b1 = (const float*)d_in[6];
  const float* g1 = (const float*)d_in[7];
  const float* be1 = (const float*)d_in[8];
  const float* W2 = (const float*)d_in[9];
  const float* b2 = (const float*)d_in[10];
  const float* g2 = (const float*)d_in[11];
  const float* be2 = (const float*)d_in[12];
  float* out = (float*)d_out;
  int E = in_sizes[1];

  char* ws = (char*)d_ws;
  unsigned short* agg_bf = (unsigned short*)(ws + 0);        // 25.6 MB
  unsigned short* v_bf = (unsigned short*)(ws + 25600000);   // 25.6 MB
  // pstats/pred overlay the v_bf region (v_bf dead after gather)
  float* pstats1 = (float*)(ws + 25600000);                  // NGB*512 floats
  float* pstats2 = (float*)(ws + 27201536);                  // NGB*256 floats
  float* pred1 = (float*)(ws + 28803072);                    // NRED*512 floats
  float* pred2 = (float*)(ws + 28934144);                    // NRED*256 floats
  unsigned short* h1_bf = (unsigned short*)(ws + 51200000);  // 51.2 MB
  uint2* spack = (uint2*)(ws + 51200000);                    // overlay (12.8 MB)
  uint2* spack2 = (uint2*)(ws + 64000000);                   // overlay (12.8 MB)
  unsigned short* w1t = (unsigned short*)(ws + 102400000);
  unsigned short* w2t = (unsigned short*)(ws + 102465536);
  float* ss1 = (float*)(ws + 102533120);
  float* ss2 = (float*)(ws + 102536192);
  int* bucket_cnt = (int*)(ws + 102537216);    // 782 ints
  int* bucket_start = (int*)(ws + 102540352);  // 783 ints
  int* gcursor = (int*)(ws + 102543488);       // 782 ints
  int* row_start = (int*)(ws + 102546688);     // 100001 ints

  hipMemsetAsync(bucket_cnt, 0, NBUK * sizeof(int), stream);

  // conv (v + weights) and bucket-hist fused into one launch (independent chains)
  conv_kernel<<<NVB + 512, 256, 0, stream>>>(v, v_bf, W1, W2, w1t, w2t,
                                             erows, bucket_cnt, E);

  scan_kernel<<<1, 256, 0, stream>>>(bucket_cnt, bucket_start, gcursor);
  bin_kernel<<<(E + BCHUNK - 1) / BCHUNK, 256, 0, stream>>>(erows, ecols, evals, gcursor, spack, E);
  sort_kernel<<<NBUK, 256, 0, stream>>>(bucket_start, spack, spack2, row_start);

  gather_kernel<<<(N_NODES + 3) / 4, 256, 0, stream>>>(row_start, spack2, v_bf, eps, agg_bf);

  gemm1_kernel<<<dim3(NGB, 2), 256, 0, stream>>>(agg_bf, w1t, b1, h1_bf, pstats1);
  reduce_kernel<512><<<NRED, 512, 0, stream>>>(pstats1, pred1);
  finalize1_kernel<<<1, 512, 0, stream>>>(pred1, g1, be1, ss1);
  gemm2_kernel<<<dim3(NGB, 2), 256, 0, stream>>>(h1_bf, ss1, w2t, b2, out, pstats2);
  reduce_kernel<256><<<NRED, 256, 0, stream>>>(pstats2, pred2);
  finalize2_kernel<<<1, 256, 0, stream>>>(pred2, g2, be2, ss2);
  bnrelu_kernel<<<2048, 256, 0, stream>>>(out, ss2);
}

// Round 14
// 239.902 us; speedup vs baseline: 1.5013x; 1.0163x over previous
//
#include <hip/hip_runtime.h>
#include <hip/hip_bf16.h>

#define N_NODES 100000
#define D_IN 128
#define D_HID 256
#define D_OUTC 128
#define BN_EPS 1e-5f
#define NBUK 782      // ceil(100000 / 128) buckets of 128 rows
#define BCHUNK 4096   // edges per bin block
#define NGB 782       // gemm row-blocks (128 rows each)
#define NRED 64       // stage-A reduction blocks
#define ROWS_PER 13   // ceil(NGB / NRED)
#define NVB 6250      // conv_v blocks (N*16/256)

typedef __attribute__((ext_vector_type(8))) short short8;
typedef __attribute__((ext_vector_type(4))) float f32x4;

__device__ __forceinline__ unsigned short f2bf(float f) {
  unsigned int u = __float_as_uint(f);
  unsigned int r = u + 0x7fffu + ((u >> 16) & 1u);
  return (unsigned short)(r >> 16);
}
__device__ __forceinline__ float bf2f(unsigned int h) {
  return __uint_as_float(h << 16);
}

// ===== fused conv + bucket-hist =====
__global__ __launch_bounds__(256) void conv_kernel(const float* __restrict__ v,
                                                   unsigned short* __restrict__ v_bf,
                                                   const float* __restrict__ W1,
                                                   const float* __restrict__ W2,
                                                   unsigned short* __restrict__ w1t,
                                                   unsigned short* __restrict__ w2t,
                                                   const int* __restrict__ erows,
                                                   int* __restrict__ bucket_cnt, int E) {
  __shared__ int lh[NBUK];
  int b = blockIdx.x;
  int tid = threadIdx.x;
  if (b < NVB) {
    int i = b * 256 + tid;
    const float4* v4 = reinterpret_cast<const float4*>(v);
    float4 a = v4[i * 2];
    float4 c = v4[i * 2 + 1];
    short8 o;
    o[0] = (short)f2bf(a.x); o[1] = (short)f2bf(a.y);
    o[2] = (short)f2bf(a.z); o[3] = (short)f2bf(a.w);
    o[4] = (short)f2bf(c.x); o[5] = (short)f2bf(c.y);
    o[6] = (short)f2bf(c.z); o[7] = (short)f2bf(c.w);
    *reinterpret_cast<short8*>(v_bf + (size_t)i * 8) = o;
  } else if (b < NVB + 256) {
    int idx = (b - NVB) * 256 + tid;
    if (idx < 128 * 256) {
      int n = idx >> 7, k = idx & 127;
      w1t[idx] = f2bf(W1[(size_t)k * 256 + n]);
    } else {
      int i2 = idx - 128 * 256;
      int n = i2 >> 8, k = i2 & 255;
      w2t[i2] = f2bf(W2[(size_t)k * 128 + n]);
    }
  } else {
    int hb = b - NVB - 256;  // 0..255
    for (int j = tid; j < NBUK; j += 256) lh[j] = 0;
    __syncthreads();
    for (int e = hb * 256 + tid; e < E; e += 256 * 256)
      atomicAdd(&lh[erows[e] >> 7], 1);
    __syncthreads();
    for (int j = tid; j < NBUK; j += 256) {
      int h = lh[j];
      if (h) atomicAdd(&bucket_cnt[j], h);
    }
  }
}

// ============ bucket scan ============
__global__ __launch_bounds__(256) void scan_kernel(const int* __restrict__ bucket_cnt,
                                                   int* __restrict__ bucket_start,
                                                   int* __restrict__ gcursor) {
  __shared__ int psum[256];
  int tid = threadIdx.x;
  int c4[4];
  int s = 0;
#pragma unroll
  for (int m = 0; m < 4; ++m) {
    int b = tid * 4 + m;
    c4[m] = (b < NBUK) ? bucket_cnt[b] : 0;
    s += c4[m];
  }
  psum[tid] = s;
  __syncthreads();
  for (int off = 1; off < 256; off <<= 1) {
    int t2 = (tid >= off) ? psum[tid - off] : 0;
    __syncthreads();
    psum[tid] += t2;
    __syncthreads();
  }
  int run = psum[tid] - s;
#pragma unroll
  for (int m = 0; m < 4; ++m) {
    int b = tid * 4 + m;
    if (b < NBUK) {
      bucket_start[b] = run;
      gcursor[b] = run;
      run += c4[m];
    }
  }
  if (tid == 255) bucket_start[NBUK] = run;  // = E
}

// ============ bin: LDS-staged bucket append with coalesced runs ============
__global__ __launch_bounds__(256) void bin_kernel(const int* __restrict__ erows,
                                                  const int* __restrict__ ecols,
                                                  const float* __restrict__ evals,
                                                  int* __restrict__ gcursor,
                                                  uint2* __restrict__ spack, int E) {
  __shared__ int lhist[NBUK], lpref[NBUK], lcur[NBUK], gbase[NBUK];
  __shared__ int psum[256];
  __shared__ uint2 pay[BCHUNK];
  __shared__ int dst[BCHUNK];
  int tid = threadIdx.x;
  int base = blockIdx.x * BCHUNK;
  int cnt = min(BCHUNK, E - base);

  for (int b = tid; b < NBUK; b += 256) lhist[b] = 0;
  __syncthreads();
#pragma unroll
  for (int k = 0; k < BCHUNK / 256; ++k) {
    int e = base + k * 256 + tid;
    if (e < E) atomicAdd(&lhist[erows[e] >> 7], 1);
  }
  __syncthreads();
  int c4[4];
  int s = 0;
#pragma unroll
  for (int m = 0; m < 4; ++m) {
    int b = tid * 4 + m;
    c4[m] = (b < NBUK) ? lhist[b] : 0;
    s += c4[m];
  }
  psum[tid] = s;
  __syncthreads();
  for (int off = 1; off < 256; off <<= 1) {
    int t2 = (tid >= off) ? psum[tid - off] : 0;
    __syncthreads();
    psum[tid] += t2;
    __syncthreads();
  }
  int run = psum[tid] - s;
#pragma unroll
  for (int m = 0; m < 4; ++m) {
    int b = tid * 4 + m;
    if (b < NBUK) {
      lpref[b] = run;
      lcur[b] = run;
      run += c4[m];
    }
  }
  for (int b = tid; b < NBUK; b += 256) {
    int h = lhist[b];
    gbase[b] = h ? atomicAdd(&gcursor[b], h) : 0;
  }
  __syncthreads();
#pragma unroll
  for (int k = 0; k < BCHUNK / 256; ++k) {
    int e = base + k * 256 + tid;
    if (e < E) {
      int row = erows[e];
      int b = row >> 7, rl = row & 127;
      int pos = atomicAdd(&lcur[b], 1);
      pay[pos] = make_uint2((unsigned)ecols[e] | ((unsigned)rl << 17),
                            __float_as_uint(evals[e]));
      dst[pos] = gbase[b] + (pos - lpref[b]);
    }
  }
  __syncthreads();
  for (int i = tid; i < cnt; i += 256) spack[dst[i]] = pay[i];
}

// ============ sort: within-bucket counting sort to node order + node row_start ============
__global__ __launch_bounds__(256) void sort_kernel(const int* __restrict__ bucket_start,
                                                   const uint2* __restrict__ spack,
                                                   uint2* __restrict__ spack2,
                                                   int* __restrict__ row_start) {
  __shared__ int lhist[128], lcur[128], buf[128];
  int tid = threadIdx.x;
  int bid = blockIdx.x;
  int s = bucket_start[bid], e = bucket_start[bid + 1];
  if (tid < 128) lhist[tid] = 0;
  __syncthreads();
  for (int i = s + tid; i < e; i += 256)
    atomicAdd(&lhist[(spack[i].x >> 17) & 127], 1);
  __syncthreads();
  if (tid < 128) buf[tid] = lhist[tid];
  __syncthreads();
  for (int off = 1; off < 128; off <<= 1) {
    int t = (tid >= off && tid < 128) ? buf[tid - off] : 0;
    __syncthreads();
    if (tid < 128) buf[tid] += t;
    __syncthreads();
  }
  if (tid < 128) {
    int excl = buf[tid] - lhist[tid];
    lcur[tid] = excl;
    int grow = bid * 128 + tid;
    if (grow <= N_NODES) row_start[grow] = s + excl;
  }
  __syncthreads();
  for (int i = s + tid; i < e; i += 256) {
    uint2 p = spack[i];
    int rl = (p.x >> 17) & 127;
    int pos = atomicAdd(&lcur[rl], 1);
    spack2[s + pos] = make_uint2(p.x & 0x1FFFFu, p.y);
  }
}

// ============ node gather: 1 wave/node, 8 edges in flight, register accum ============
__global__ __launch_bounds__(256) void gather_kernel(const int* __restrict__ row_start,
                                                     const uint2* __restrict__ spack2,
                                                     const unsigned short* __restrict__ v_bf,
                                                     const float* __restrict__ eps_p,
                                                     unsigned short* __restrict__ agg_bf) {
  int wid = blockIdx.x * 4 + (threadIdx.x >> 6);
  if (wid >= N_NODES) return;
  int lane = threadIdx.x & 63;
  int half = lane >> 5;
  int l5 = lane & 31;
  int s = row_start[wid];
  int end = row_start[wid + 1];
  const uint2* v64 = reinterpret_cast<const uint2*>(v_bf);

  float a0 = 0.f, a1 = 0.f, a2 = 0.f, a3 = 0.f;
  for (int e = s; e < end; e += 8) {
    uint2 p[4];
#pragma unroll
    for (int j = 0; j < 4; ++j) p[j] = spack2[min(e + 2 * j + half, end - 1)];
    uint2 t[4];
#pragma unroll
    for (int j = 0; j < 4; ++j) t[j] = v64[(size_t)p[j].x * 32 + l5];
#pragma unroll
    for (int j = 0; j < 4; ++j) {
      float w = (e + 2 * j + half < end) ? __uint_as_float(p[j].y) : 0.f;
      a0 += w * bf2f(t[j].x & 0xffffu);
      a1 += w * bf2f(t[j].x >> 16);
      a2 += w * bf2f(t[j].y & 0xffffu);
      a3 += w * bf2f(t[j].y >> 16);
    }
  }
  a0 += __shfl_xor(a0, 32);
  a1 += __shfl_xor(a1, 32);
  a2 += __shfl_xor(a2, 32);
  a3 += __shfl_xor(a3, 32);
  if (half == 0) {
    float eps = eps_p[0];
    uint2 tv = v64[(size_t)wid * 32 + l5];
    a0 += eps * bf2f(tv.x & 0xffffu);
    a1 += eps * bf2f(tv.x >> 16);
    a2 += eps * bf2f(tv.y & 0xffffu);
    a3 += eps * bf2f(tv.y >> 16);
    uint2 o;
    o.x = (unsigned)f2bf(a0) | ((unsigned)f2bf(a1) << 16);
    o.y = (unsigned)f2bf(a2) | ((unsigned)f2bf(a3) << 16);
    reinterpret_cast<uint2*>(agg_bf)[(size_t)wid * 32 + l5] = o;
  }
}

// ============ GEMM1: block = 128 rows x 128 cols (ch half), 32KB LDS ============
__global__ __launch_bounds__(256) void gemm1_kernel(const unsigned short* __restrict__ agg_bf,
                                                    const unsigned short* __restrict__ w1t,
                                                    const float* __restrict__ b1,
                                                    unsigned short* __restrict__ h1_bf,
                                                    float* __restrict__ pstats1) {
  __shared__ unsigned char smem[32768];
  int tid = threadIdx.x;
  int wid = tid >> 6;
  int lane = tid & 63;
  int m15 = lane & 15;
  int g8 = (lane >> 4) * 8;
  int g16 = (lane >> 4) * 16;
  int q4 = lane >> 4;
  int bx = blockIdx.x, ch = blockIdx.y;
  int row0 = bx * 128;
  int wrow = row0 + wid * 32;

  short8 a0[4], a1[4];
  {
    const unsigned short* A0 = agg_bf + (size_t)min(wrow + m15, N_NODES - 1) * 128 + g8;
    const unsigned short* A1 = agg_bf + (size_t)min(wrow + 16 + m15, N_NODES - 1) * 128 + g8;
#pragma unroll
    for (int s = 0; s < 4; ++s) {
      a0[s] = *reinterpret_cast<const short8*>(A0 + s * 32);
      a1[s] = *reinterpret_cast<const short8*>(A1 + s * 32);
    }
  }
  {
    const float4* src = reinterpret_cast<const float4*>(w1t + (size_t)ch * 128 * 128);
#pragma unroll
    for (int it = 0; it < 8; ++it) {
      int i = it * 256 + tid;
      int lrow = i >> 4;
      int cb = (i & 15) << 4;
      *reinterpret_cast<float4*>(smem + lrow * 256 + (cb ^ ((lrow & 7) << 4))) = src[i];
    }
  }
  __syncthreads();

  f32x4 acc0[8], acc1[8];
#pragma unroll
  for (int t = 0; t < 8; ++t) {
    acc0[t] = (f32x4){0.f, 0.f, 0.f, 0.f};
    acc1[t] = (f32x4){0.f, 0.f, 0.f, 0.f};
  }
#pragma unroll
  for (int s = 0; s < 4; ++s) {
#pragma unroll
    for (int t = 0; t < 8; ++t) {
      int lrow = t * 16 + m15;
      short8 b = *reinterpret_cast<const short8*>(
          smem + lrow * 256 + ((s * 64 + g16) ^ ((lrow & 7) << 4)));
      acc0[t] = __builtin_amdgcn_mfma_f32_16x16x32_bf16(a0[s], b, acc0[t], 0, 0, 0);
      acc1[t] = __builtin_amdgcn_mfma_f32_16x16x32_bf16(a1[s], b, acc1[t], 0, 0, 0);
    }
  }
  __syncthreads();  // B dead; reuse for 128x128 bf16 repack (32KB)

  unsigned short* lds16 = reinterpret_cast<unsigned short*>(smem);
#pragma unroll
  for (int t = 0; t < 8; ++t) {
    int lcol = t * 16 + m15;
    float bias = b1[ch * 128 + lcol];
    int sw = lcol ^ (q4 << 4);
#pragma unroll
    for (int r = 0; r < 4; ++r) {
      int rl0 = wid * 32 + q4 * 4 + r;
      int rl1 = rl0 + 16;
      lds16[rl0 * 128 + sw] = f2bf(acc0[t][r] + bias);
      lds16[rl1 * 128 + sw] = f2bf(acc1[t][r] + bias);
    }
  }
  __syncthreads();
#pragma unroll
  for (int it = 0; it < 8; ++it) {
    int cid = it * 256 + tid;
    int rl = cid >> 4, c8 = (cid & 15) * 8;
    int row = row0 + rl;
    if (row < N_NODES) {
      *reinterpret_cast<short8*>(h1_bf + (size_t)row * 256 + ch * 128 + c8) =
          *reinterpret_cast<const short8*>(&lds16[rl * 128 + (c8 ^ (((rl >> 2) & 3) << 4))]);
    }
  }
  {
    int nvalid = min(128, N_NODES - row0);
    int col = tid & 127, kind = tid >> 7;
    float acc = 0.f;
    for (int rl = 0; rl < nvalid; ++rl) {
      float x = bf2f((unsigned int)lds16[rl * 128 + (col ^ (((rl >> 2) & 3) << 4))]);
      acc += kind ? x * x : x;
    }
    pstats1[(size_t)bx * 512 + ch * 256 + kind * 128 + col] = acc;
  }
}

// ============ stage-A reduce: pstats[NGB][W] -> pred[NRED][W] ============
template <int W>
__global__ void reduce_kernel(const float* __restrict__ pstats, float* __restrict__ pred) {
  int j = threadIdx.x;
  int r0 = blockIdx.x * ROWS_PER;
  int r1 = min(r0 + ROWS_PER, NGB);
  float s = 0.f;
  for (int i = r0; i < r1; ++i) s += pstats[(size_t)i * W + j];
  pred[(size_t)blockIdx.x * W + j] = s;
}

// ============ finalize1: reduce NRED partials -> ss1 (scale/shift, 256 cols) ============
__global__ __launch_bounds__(512) void finalize1_kernel(const float* __restrict__ pred,
                                                        const float* __restrict__ g,
                                                        const float* __restrict__ be,
                                                        float* __restrict__ ss) {
  __shared__ float red[512];
  int j = threadIdx.x;
  float s = 0.f;
#pragma unroll 8
  for (int i = 0; i < NRED; ++i) s += pred[(size_t)i * 512 + j];
  red[j] = s;
  __syncthreads();
  if (j < 256) {
    int ch = j >> 7, lc = j & 127;
    float sum = red[ch * 256 + lc];
    float sq = red[ch * 256 + 128 + lc];
    float inv_n = 1.0f / (float)N_NODES;
    float mu = sum * inv_n;
    float var = sq * inv_n - mu * mu;
    float sc = g[j] * rsqrtf(var + BN_EPS);
    ss[j] = sc;
    ss[256 + j] = be[j] - mu * sc;
  }
}

// ============ GEMM2: block = 128 rows x 64 cols (ch half), 32KB LDS, bf16 h2 out ============
__global__ __launch_bounds__(256) void gemm2_kernel(const unsigned short* __restrict__ h1_bf,
                                                    const float* __restrict__ ss1,
                                                    const unsigned short* __restrict__ w2t,
                                                    const float* __restrict__ b2,
                                                    unsigned short* __restrict__ h2_bf,
                                                    float* __restrict__ pstats2) {
  __shared__ unsigned char smem[32768];
  int tid = threadIdx.x;
  int wid = tid >> 6;
  int lane = tid & 63;
  int m15 = lane & 15;
  int g8 = (lane >> 4) * 8;
  int g16 = (lane >> 4) * 16;
  int q4 = lane >> 4;
  int bx = blockIdx.x, ch = blockIdx.y;
  int row0 = bx * 128;
  int wrow = row0 + wid * 32;

  short8 a0[8], a1[8];
  {
    const unsigned short* A0 = h1_bf + (size_t)min(wrow + m15, N_NODES - 1) * 256 + g8;
    const unsigned short* A1 = h1_bf + (size_t)min(wrow + 16 + m15, N_NODES - 1) * 256 + g8;
#pragma unroll
    for (int s = 0; s < 8; ++s) {
      a0[s] = *reinterpret_cast<const short8*>(A0 + s * 32);
      a1[s] = *reinterpret_cast<const short8*>(A1 + s * 32);
    }
  }
  {
    const float4* src = reinterpret_cast<const float4*>(w2t + (size_t)ch * 64 * 256);
#pragma unroll
    for (int it = 0; it < 8; ++it) {
      int i = it * 256 + tid;
      int lrow = i >> 5;
      int cb = (i & 31) << 4;
      *reinterpret_cast<float4*>(smem + lrow * 512 + (cb ^ ((lrow & 7) << 4))) = src[i];
    }
  }
#pragma unroll
  for (int s = 0; s < 8; ++s) {
    int k0 = s * 32 + g8;
    float scv[8], shv[8];
    *reinterpret_cast<float4*>(&scv[0]) = *reinterpret_cast<const float4*>(ss1 + k0);
    *reinterpret_cast<float4*>(&scv[4]) = *reinterpret_cast<const float4*>(ss1 + k0 + 4);
    *reinterpret_cast<float4*>(&shv[0]) = *reinterpret_cast<const float4*>(ss1 + 256 + k0);
    *reinterpret_cast<float4*>(&shv[4]) = *reinterpret_cast<const float4*>(ss1 + 256 + k0 + 4);
#pragma unroll
    for (int j = 0; j < 8; ++j) {
      a0[s][j] = (short)f2bf(fmaxf(bf2f((unsigned int)(unsigned short)a0[s][j]) * scv[j] + shv[j], 0.f));
      a1[s][j] = (short)f2bf(fmaxf(bf2f((unsigned int)(unsigned short)a1[s][j]) * scv[j] + shv[j], 0.f));
    }
  }
  __syncthreads();

  f32x4 acc0[4], acc1[4];
#pragma unroll
  for (int t = 0; t < 4; ++t) {
    acc0[t] = (f32x4){0.f, 0.f, 0.f, 0.f};
    acc1[t] = (f32x4){0.f, 0.f, 0.f, 0.f};
  }
#pragma unroll
  for (int s = 0; s < 8; ++s) {
#pragma unroll
    for (int t = 0; t < 4; ++t) {
      int lrow = t * 16 + m15;
      short8 b = *reinterpret_cast<const short8*>(
          smem + lrow * 512 + ((s * 64 + g16) ^ ((lrow & 7) << 4)));
      acc0[t] = __builtin_amdgcn_mfma_f32_16x16x32_bf16(a0[s], b, acc0[t], 0, 0, 0);
      acc1[t] = __builtin_amdgcn_mfma_f32_16x16x32_bf16(a1[s], b, acc1[t], 0, 0, 0);
    }
  }
  __syncthreads();  // B dead; reuse for 128x64 bf16 repack (16KB)

  unsigned short* lds16 = reinterpret_cast<unsigned short*>(smem);
#pragma unroll
  for (int t = 0; t < 4; ++t) {
    int lcol = t * 16 + m15;
    float bias = b2[ch * 64 + lcol];
    int sw = lcol ^ (q4 << 4);
#pragma unroll
    for (int r = 0; r < 4; ++r) {
      int rl0 = wid * 32 + q4 * 4 + r;
      int rl1 = rl0 + 16;
      lds16[rl0 * 64 + sw] = f2bf(acc0[t][r] + bias);
      lds16[rl1 * 64 + sw] = f2bf(acc1[t][r] + bias);
    }
  }
  __syncthreads();
  // coalesced store of the 128x64 bf16 col-slice
#pragma unroll
  for (int it = 0; it < 4; ++it) {
    int cid = it * 256 + tid;
    int rl = cid >> 3, c8 = (cid & 7) * 8;
    int row = row0 + rl;
    if (row < N_NODES) {
      *reinterpret_cast<short8*>(h2_bf + (size_t)row * 128 + ch * 64 + c8) =
          *reinterpret_cast<const short8*>(&lds16[rl * 64 + (c8 ^ (((rl >> 2) & 3) << 4))]);
    }
  }
  // partial BN2 stats from the bf16-rounded values (consistent with bnrelu's input)
  if (tid < 128) {
    int nvalid = min(128, N_NODES - row0);
    int col = tid & 63, kind = tid >> 6;
    float acc = 0.f;
    for (int rl = 0; rl < nvalid; ++rl) {
      float x = bf2f((unsigned int)lds16[rl * 64 + (col ^ (((rl >> 2) & 3) << 4))]);
      acc += kind ? x * x : x;
    }
    pstats2[(size_t)bx * 256 + ch * 128 + kind * 64 + col] = acc;
  }
}

// ============ finalize2: reduce NRED partials -> ss2 (128 cols) ============
__global__ __launch_bounds__(256) void finalize2_kernel(const float* __restrict__ pred,
                                                        const float* __restrict__ g,
                                                        const float* __restrict__ be,
                                                        float* __restrict__ ss) {
  __shared__ float red[256];
  int j = threadIdx.x;
  float s = 0.f;
#pragma unroll 8
  for (int i = 0; i < NRED; ++i) s += pred[(size_t)i * 256 + j];
  red[j] = s;
  __syncthreads();
  if (j < 128) {
    int ch = j >> 6, lc = j & 63;
    float sum = red[ch * 128 + lc];
    float sq = red[ch * 128 + 64 + lc];
    float inv_n = 1.0f / (float)N_NODES;
    float mu = sum * inv_n;
    float var = sq * inv_n - mu * mu;
    float sc = g[j] * rsqrtf(var + BN_EPS);
    ss[j] = sc;
    ss[128 + j] = be[j] - mu * sc;
  }
}

// ============ bnrelu: read bf16 h2, apply BN2+ReLU, write fp32 out ============
__global__ __launch_bounds__(256) void bnrelu_kernel(const unsigned short* __restrict__ h2_bf,
                                                     float* __restrict__ out,
                                                     const float* __restrict__ ss) {
  __shared__ float sc[D_OUTC], sh[D_OUTC];
  if (threadIdx.x < D_OUTC) {
    sc[threadIdx.x] = ss[threadIdx.x];
    sh[threadIdx.x] = ss[D_OUTC + threadIdx.x];
  }
  __syncthreads();
  size_t total = (size_t)N_NODES * 16;  // 8 bf16 per chunk
  for (size_t i = (size_t)blockIdx.x * blockDim.x + threadIdx.x; i < total;
       i += (size_t)gridDim.x * blockDim.x) {
    short8 hv = *reinterpret_cast<const short8*>(h2_bf + i * 8);
    int c0 = ((int)(i & 15)) * 8;
    float4 o0, o1;
    o0.x = fmaxf(bf2f((unsigned int)(unsigned short)hv[0]) * sc[c0 + 0] + sh[c0 + 0], 0.f);
    o0.y = fmaxf(bf2f((unsigned int)(unsigned short)hv[1]) * sc[c0 + 1] + sh[c0 + 1], 0.f);
    o0.z = fmaxf(bf2f((unsigned int)(unsigned short)hv[2]) * sc[c0 + 2] + sh[c0 + 2], 0.f);
    o0.w = fmaxf(bf2f((unsigned int)(unsigned short)hv[3]) * sc[c0 + 3] + sh[c0 + 3], 0.f);
    o1.x = fmaxf(bf2f((unsigned int)(unsigned short)hv[4]) * sc[c0 + 4] + sh[c0 + 4], 0.f);
    o1.y = fmaxf(bf2f((unsigned int)(unsigned short)hv[5]) * sc[c0 + 5] + sh[c0 + 5], 0.f);
    o1.z = fmaxf(bf2f((unsigned int)(unsigned short)hv[6]) * sc[c0 + 6] + sh[c0 + 6], 0.f);
    o1.w = fmaxf(bf2f((unsigned int)(unsigned short)hv[7]) * sc[c0 + 7] + sh[c0 + 7], 0.f);
    reinterpret_cast<float4*>(out)[i * 2] = o0;
    reinterpret_cast<float4*>(out)[i * 2 + 1] = o1;
  }
}

extern "C" void kernel_launch(void* const* d_in, const int* in_sizes, int n_in,
                              void* d_out, int out_size, void* d_ws, size_t ws_size,
                              hipStream_t stream) {
  const float* v = (const float*)d_in[0];
  const int* erows = (const int*)d_in[1];
  const int* ecols = (const int*)d_in[2];
  const float* evals = (const float*)d_in[3];
  const float* eps = (const float*)d_in[4];
  const float* W1 = (const float*)d_in[5];
  const float* b1 = (const float*)d_in[6];
  const float* g1 = (const float*)d_in[7];
  const float* be1 = (const float*)d_in[8];
  const float* W2 = (const float*)d_in[9];
  const float* b2 = (const float*)d_in[10];
  const float* g2 = (const float*)d_in[11];
  const float* be2 = (const float*)d_in[12];
  float* out = (float*)d_out;
  int E = in_sizes[1];

  char* ws = (char*)d_ws;
  unsigned short* agg_bf = (unsigned short*)(ws + 0);        // 25.6 MB (dead after gemm1)
  unsigned short* h2_bf = (unsigned short*)(ws + 0);         // overlay agg (gemm2 output)
  unsigned short* v_bf = (unsigned short*)(ws + 25600000);   // 25.6 MB
  // pstats/pred overlay the v_bf region (v_bf dead after gather)
  float* pstats1 = (float*)(ws + 25600000);                  // NGB*512 floats
  float* pstats2 = (float*)(ws + 27201536);                  // NGB*256 floats
  float* pred1 = (float*)(ws + 28803072);                    // NRED*512 floats
  float* pred2 = (float*)(ws + 28934144);                    // NRED*256 floats
  unsigned short* h1_bf = (unsigned short*)(ws + 51200000);  // 51.2 MB
  uint2* spack = (uint2*)(ws + 51200000);                    // overlay (12.8 MB, dead after sort)
  uint2* spack2 = (uint2*)(ws + 64000000);                   // overlay (12.8 MB)
  unsigned short* w1t = (unsigned short*)(ws + 102400000);
  unsigned short* w2t = (unsigned short*)(ws + 102465536);
  float* ss1 = (float*)(ws + 102533120);
  float* ss2 = (float*)(ws + 102536192);
  int* bucket_cnt = (int*)(ws + 102537216);    // 782 ints
  int* bucket_start = (int*)(ws + 102540352);  // 783 ints
  int* gcursor = (int*)(ws + 102543488);       // 782 ints
  int* row_start = (int*)(ws + 102546688);     // 100001 ints

  hipMemsetAsync(bucket_cnt, 0, NBUK * sizeof(int), stream);

  conv_kernel<<<NVB + 512, 256, 0, stream>>>(v, v_bf, W1, W2, w1t, w2t,
                                             erows, bucket_cnt, E);

  scan_kernel<<<1, 256, 0, stream>>>(bucket_cnt, bucket_start, gcursor);
  bin_kernel<<<(E + BCHUNK - 1) / BCHUNK, 256, 0, stream>>>(erows, ecols, evals, gcursor, spack, E);
  sort_kernel<<<NBUK, 256, 0, stream>>>(bucket_start, spack, spack2, row_start);

  gather_kernel<<<(N_NODES + 3) / 4, 256, 0, stream>>>(row_start, spack2, v_bf, eps, agg_bf);

  gemm1_kernel<<<dim3(NGB, 2), 256, 0, stream>>>(agg_bf, w1t, b1, h1_bf, pstats1);
  reduce_kernel<512><<<NRED, 512, 0, stream>>>(pstats1, pred1);
  finalize1_kernel<<<1, 512, 0, stream>>>(pred1, g1, be1, ss1);
  gemm2_kernel<<<dim3(NGB, 2), 256, 0, stream>>>(h1_bf, ss1, w2t, b2, h2_bf, pstats2);
  reduce_kernel<256><<<NRED, 256, 0, stream>>>(pstats2, pred2);
  finalize2_kernel<<<1, 256, 0, stream>>>(pred2, g2, be2, ss2);
  bnrelu_kernel<<<2048, 256, 0, stream>>>(h2_bf, out, ss2);
}